// Round 5
// baseline (1096.291 us; speedup 1.0000x reference)
//
#include <hip/hip_runtime.h>
#include <stdint.h>

#define B_ 4
#define C_ 256
#define N_ 4096
#define L2E 1.4426950408889634f

typedef unsigned short u16;
typedef unsigned int u32;
typedef float f32x4 __attribute__((ext_vector_type(4)));
typedef __bf16 bf16x8 __attribute__((ext_vector_type(8)));

union U16x8 { uint4 q; bf16x8 v; u16 u[8]; __bf16 h[8]; };
union BF2 { u32 w; __bf16 h[2]; };

__device__ __forceinline__ bf16x8 ld_bf8(const u16* p) {
  U16x8 t; t.q = *(const uint4*)p; return t.v;
}
__device__ __forceinline__ f32x4 mfma16(bf16x8 a, bf16x8 b, f32x4 c) {
  return __builtin_amdgcn_mfma_f32_16x16x32_bf16(a, b, c, 0, 0, 0);
}

// ---------------- K-prep: weight conversions ----------------
__global__ __launch_bounds__(256) void k_prep(const float* __restrict__ vw, const float* __restrict__ tw,
                                              const float* __restrict__ qkw,
                                              u16* __restrict__ wv, u16* __restrict__ wt, float* __restrict__ wqkt) {
  int i = blockIdx.x * 256 + threadIdx.x;
  int stride = gridDim.x * 256;
  for (int idx = i; idx < C_ * C_; idx += stride) {
    BF2 a, b; a.h[0] = (__bf16)vw[idx]; b.h[0] = (__bf16)tw[idx];
    wv[idx] = (u16)(a.w & 0xFFFF);
    wt[idx] = (u16)(b.w & 0xFFFF);
  }
  for (int idx = i; idx < 32 * C_; idx += stride) {
    int c = idx >> 8, cin = idx & 255;
    wqkt[cin * 32 + c] = qkw[idx];           // transposed, fp32 (exponent-accuracy path)
  }
}

// ---------------- K-xt: x [b][c][n] fp32 -> x_t [b][n][c] bf16 ----------------
__global__ __launch_bounds__(256) void k_xt(const float* __restrict__ x, u16* __restrict__ xt) {
  int bid = blockIdx.x;
  int cb = bid & 3, nt = (bid >> 2) & 63, b = bid >> 8;
  __shared__ u16 tile[64][66];
  int t = threadIdx.x, nl = t & 63, cg = t >> 6;
  const float* xp = x + ((size_t)b * C_ + cb * 64) * N_ + nt * 64;
  #pragma unroll
  for (int cc = 0; cc < 16; ++cc) {
    int c = cg * 16 + cc;
    BF2 v; v.h[0] = (__bf16)xp[(size_t)c * N_ + nl];
    tile[c][nl] = (u16)(v.w & 0xFFFF);
  }
  __syncthreads();
  u16* op = xt + ((size_t)b * N_ + nt * 64) * C_ + cb * 64;
  #pragma unroll
  for (int nn = 0; nn < 16; ++nn) {
    int n2 = cg * 16 + nn;
    op[(size_t)n2 * C_ + nl] = tile[nl][n2];
  }
}

// ---------------- K-qk: fp32 GEMM + bn1/bn2 + relu -> q',k' bf16 [b][n][32] ----------------
// qsg = (sum_c q) * log2(e)  [scaled domain for exp2]; ksg = sum_c k (raw).
__global__ __launch_bounds__(256) void k_qk(
    const float* __restrict__ x, const float* __restrict__ wqkt,
    const float* __restrict__ bn1s, const float* __restrict__ bn1b,
    const float* __restrict__ bn2s, const float* __restrict__ bn2b,
    u16* __restrict__ qb, u16* __restrict__ kb,
    float* __restrict__ qsg, float* __restrict__ ksg) {
  int bid = blockIdx.x;
  bid = (bid & 7) * 32 + (bid >> 3);
  int nt = bid & 63, b = bid >> 6;
  int t = threadIdx.x;
  int nl = t & 63;
  int qg = __builtin_amdgcn_readfirstlane(t >> 6);
  int n = nt * 64 + nl;

  __shared__ float red[4][64][33];
  __shared__ float qsum[4][64], ksum[4][64];

  float acc[32];
  #pragma unroll
  for (int c = 0; c < 32; ++c) acc[c] = 0.f;

  const float* xp = x + ((size_t)b * C_ + qg * 64) * N_ + n;
  const float* wp = wqkt + qg * 64 * 32;
  for (int i = 0; i < 64; ++i) {
    float xvv = xp[(size_t)i * N_];
    const float* wr = wp + i * 32;
    #pragma unroll
    for (int c = 0; c < 32; ++c) acc[c] = fmaf(wr[c], xvv, acc[c]);
  }
  #pragma unroll
  for (int c = 0; c < 32; ++c) red[qg][nl][c] = acc[c];
  __syncthreads();

  float pqs = 0.f, pks = 0.f;
  U16x8 tq, tk;
  #pragma unroll
  for (int i2 = 0; i2 < 8; ++i2) {
    int c = qg * 8 + i2;
    float s = red[0][nl][c] + red[1][nl][c] + red[2][nl][c] + red[3][nl][c];
    float fq = fmaxf(fmaf(s, bn1s[c], bn1b[c]), 0.f);
    float fk = fmaxf(fmaf(s, bn2s[c], bn2b[c]), 0.f);
    pqs += fq; pks += fk;
    tq.h[i2] = (__bf16)fq; tk.h[i2] = (__bf16)fk;
  }
  size_t ofs = ((size_t)(b * N_ + n)) * 32 + qg * 8;
  *(uint4*)(qb + ofs) = tq.q;
  *(uint4*)(kb + ofs) = tk.q;

  qsum[qg][nl] = pqs; ksum[qg][nl] = pks;
  __syncthreads();
  if (t < 64) {
    int nn2 = nt * 64 + t;
    qsg[b * N_ + nn2] = (qsum[0][t] + qsum[1][t] + qsum[2][t] + qsum[3][t]) * L2E;
    ksg[b * N_ + nn2] = ksum[0][t] + ksum[1][t] + ksum[2][t] + ksum[3][t];
  }
}

// ---------------- K-gemm256: out[o][n] = epilogue(W[256x256] @ act^T) ----------------
// MODE 0: v-conv -> x_v bf16 [b][c][n'] with n' k-slot-permuted within each 32-block
//         (n = s*16+g*4+t -> n' = g*8+s*4+t) so phaseB's PV A-fragment is one 16B load.
// MODE 1: trans-conv + residual -> out fp32
template<int MODE>
__global__ __launch_bounds__(256) void k_gemm256(
    const u16* __restrict__ W, const u16* __restrict__ act,
    const float* __restrict__ bias, const float* __restrict__ bns, const float* __restrict__ bnb,
    const float* __restrict__ xres, u16* __restrict__ outb, float* __restrict__ outf) {
  int bid = blockIdx.x;
  bid = (bid & 7) * 64 + (bid >> 3);
  int nt = bid & 127, b = bid >> 7;
  int n0 = nt * 32;
  int t = threadIdx.x;
  int w = t >> 6, l = t & 63, lr = l & 15, lg = l >> 4;

  f32x4 acc[4][2];
  #pragma unroll
  for (int ot = 0; ot < 4; ++ot)
    #pragma unroll
    for (int ns = 0; ns < 2; ++ns) acc[ot][ns] = f32x4{0.f, 0.f, 0.f, 0.f};

  const u16* actp = act + ((size_t)b * N_ + n0) * C_;
  for (int kk = 0; kk < 8; ++kk) {
    int k0 = kk * 32;
    bf16x8 bf[2];
    #pragma unroll
    for (int ns = 0; ns < 2; ++ns)
      bf[ns] = ld_bf8(actp + (size_t)(ns * 16 + lr) * C_ + k0 + lg * 8);
    #pragma unroll
    for (int ot = 0; ot < 4; ++ot) {
      bf16x8 af = ld_bf8(W + (size_t)(w * 64 + ot * 16 + lr) * C_ + k0 + lg * 8);
      #pragma unroll
      for (int ns = 0; ns < 2; ++ns) acc[ot][ns] = mfma16(af, bf[ns], acc[ot][ns]);
    }
  }
  #pragma unroll
  for (int ot = 0; ot < 4; ++ot) {
    #pragma unroll
    for (int r = 0; r < 4; ++r) {
      int oc = w * 64 + ot * 16 + lg * 4 + r;
      float sO = bns[oc], bO = bnb[oc], biO = bias[oc];
      #pragma unroll
      for (int ns = 0; ns < 2; ++ns) {
        int nn = ns * 16 + lr;
        float val = fmaxf(fmaf(acc[ot][ns][r] + biO, sO, bO), 0.f);
        if (MODE == 0) {
          int np = ((nn >> 2) & 3) * 8 + (nn >> 4) * 4 + (nn & 3);   // k-slot permute
          size_t idx = ((size_t)b * C_ + oc) * N_ + n0 + np;
          BF2 v; v.h[0] = (__bf16)val; outb[idx] = (u16)(v.w & 0xFFFF);
        } else {
          size_t idx = ((size_t)b * C_ + oc) * N_ + n0 + nn;
          outf[idx] = xres[idx] + val;
        }
      }
    }
  }
}

// ---------------- K-phaseA: fused row stat rmg = max' + log2(sum') (scaled domain) ----------------
__global__ __launch_bounds__(512) void k_phaseA(
    const u16* __restrict__ qb, const u16* __restrict__ kb,
    const float* __restrict__ qsg, const float* __restrict__ ksg,
    float* __restrict__ rmg) {
  int bid = blockIdx.x;
  bid = (bid & 7) * 64 + (bid >> 3);
  int nt = bid & 127, b = bid >> 7;
  int bN = b * N_;
  int t = threadIdx.x;
  int w = t >> 6, l = t & 63, lr = l & 15, lg = l >> 4;
  int nsub = w & 1, mq = w >> 1;
  int nrow0 = nt * 32 + nsub * 16;

  __shared__ float pM[4][32], pS[4][32];

  bf16x8 qf = ld_bf8(qb + ((size_t)(bN + nrow0 + lr)) * 32 + lg * 8);
  f32x4 qsv = *(const f32x4*)(qsg + bN + nrow0 + lg * 4);   // already *L2E

  float Mv[4], Sv[4];
  #pragma unroll
  for (int r = 0; r < 4; ++r) { Mv[r] = -3e38f; Sv[r] = 0.f; }

  int mbase = mq * 1024;
  for (int ms = 0; ms < 16; ++ms) {
    float ev[4][4];
    #pragma unroll
    for (int mt2 = 0; mt2 < 4; ++mt2) {
      int m0 = mbase + ms * 64 + mt2 * 16;
      bf16x8 kf = ld_bf8(kb + ((size_t)(bN + m0 + lr)) * 32 + lg * 8);
      f32x4 e = mfma16(qf, kf, f32x4{0.f, 0.f, 0.f, 0.f});
      float ksv = ksg[bN + m0 + lr];
      #pragma unroll
      for (int r = 0; r < 4; ++r) ev[mt2][r] = fmaf(e[r], L2E, -qsv[r] * ksv);  // scaled e'
    }
    #pragma unroll
    for (int r = 0; r < 4; ++r) {
      float t0 = fmaxf(fmaxf(ev[0][r], ev[1][r]), fmaxf(ev[2][r], ev[3][r]));
      float Mn = fmaxf(Mv[r], t0);
      Sv[r] = Sv[r] * __builtin_amdgcn_exp2f(Mv[r] - Mn)
            + __builtin_amdgcn_exp2f(ev[0][r] - Mn)
            + __builtin_amdgcn_exp2f(ev[1][r] - Mn)
            + __builtin_amdgcn_exp2f(ev[2][r] - Mn)
            + __builtin_amdgcn_exp2f(ev[3][r] - Mn);
      Mv[r] = Mn;
    }
  }
  #pragma unroll
  for (int off = 1; off < 16; off <<= 1) {
    #pragma unroll
    for (int r = 0; r < 4; ++r) {
      float Mo = __shfl_xor(Mv[r], off);
      float So = __shfl_xor(Sv[r], off);
      float Mn = fmaxf(Mv[r], Mo);
      Sv[r] = Sv[r] * __builtin_amdgcn_exp2f(Mv[r] - Mn)
            + So   * __builtin_amdgcn_exp2f(Mo   - Mn);
      Mv[r] = Mn;
    }
  }
  if (lr == 0) {
    #pragma unroll
    for (int r = 0; r < 4; ++r) {
      pM[mq][nsub * 16 + lg * 4 + r] = Mv[r];
      pS[mq][nsub * 16 + lg * 4 + r] = Sv[r];
    }
  }
  __syncthreads();
  if (t < 32) {
    float M = fmaxf(fmaxf(pM[0][t], pM[1][t]), fmaxf(pM[2][t], pM[3][t]));
    float S = pS[0][t] * __builtin_amdgcn_exp2f(pM[0][t] - M)
            + pS[1][t] * __builtin_amdgcn_exp2f(pM[1][t] - M)
            + pS[2][t] * __builtin_amdgcn_exp2f(pM[2][t] - M)
            + pS[3][t] * __builtin_amdgcn_exp2f(pM[3][t] - M);
    rmg[bN + nt * 32 + t] = M + __builtin_amdgcn_logf(S);   // v_log_f32 = log2
  }
}

// ---------------- K-phaseB: barrier-free flash PV, n-split across waves ----------------
// 2048 blocks (b,mt128,cq4) x 256 thr = 8 blocks/CU = 32 waves/CU (8/SIMD).
// Block = (m32 tile, c64 quarter); wave w scans n-quarter w. Round-3 inner body
// (best load:MFMA ratio); PV partials summed across waves via LDS at the end.
struct Win {
  bf16x8 qf0, qf1;
  f32x4 qs0, qs1, rm0, rm1;
  uint4 vq0, vq1, vq2, vq3;
};

__global__ __launch_bounds__(256, 8) void k_phaseB(
    const u16* __restrict__ qb, const u16* __restrict__ kb,
    const float* __restrict__ qsg, const float* __restrict__ ksg,
    const float* __restrict__ rmg,
    const u16* __restrict__ xvp, const u16* __restrict__ xt,
    u16* __restrict__ diffb) {
  int bid = blockIdx.x;
  bid = (bid & 7) * 256 + (bid >> 3);      // XCD swizzle: XCD pair covers one batch's panels
  int b = bid >> 9;
  int rr = bid & 511;
  int cq = rr & 3, mt = rr >> 2;           // mt 0..127
  int m0 = mt * 32, c0 = cq * 64;
  int bN = b * N_;
  int t = threadIdx.x;
  int w = t >> 6, l = t & 63, lr = l & 15, lg = l >> 4;

  __shared__ float accl[2][8][256];        // [buf][slot(msub*4+ct)][lane*4] - contiguous b128
  __shared__ float csl[4][32];

  bf16x8 kf0 = ld_bf8(kb + (size_t)(bN + m0 + lr) * 32 + lg * 8);
  bf16x8 kf1 = ld_bf8(kb + (size_t)(bN + m0 + 16 + lr) * 32 + lg * 8);
  float ks0 = ksg[bN + m0 + lr];
  float ks1 = ksg[bN + m0 + 16 + lr];

  const u16* qbase = qb + (size_t)bN * 32;
  const float* qsb = qsg + bN;
  const float* rmb = rmg + bN;
  const u16* vbase = xvp + (size_t)(b * C_ + c0) * N_ + (size_t)lr * N_;

  f32x4 acc0[4], acc1[4];
  #pragma unroll
  for (int ct = 0; ct < 4; ++ct) {
    acc0[ct] = f32x4{0.f, 0.f, 0.f, 0.f};
    acc1[ct] = f32x4{0.f, 0.f, 0.f, 0.f};
  }
  float cs0 = 0.f, cs1 = 0.f;

  auto load_win = [&](int wd) {
    Win W;
    int nb = wd * 32;
    W.qf0 = ld_bf8(qbase + (size_t)(nb + lr) * 32 + lg * 8);
    W.qf1 = ld_bf8(qbase + (size_t)(nb + 16 + lr) * 32 + lg * 8);
    W.qs0 = *(const f32x4*)(qsb + nb + lg * 4);
    W.qs1 = *(const f32x4*)(qsb + nb + 16 + lg * 4);
    W.rm0 = *(const f32x4*)(rmb + nb + lg * 4);
    W.rm1 = *(const f32x4*)(rmb + nb + 16 + lg * 4);
    const u16* vp = vbase + nb + lg * 8;
    W.vq0 = *(const uint4*)(vp);
    W.vq1 = *(const uint4*)(vp + (size_t)16 * N_);
    W.vq2 = *(const uint4*)(vp + (size_t)32 * N_);
    W.vq3 = *(const uint4*)(vp + (size_t)48 * N_);
    return W;
  };

  int w0win = w * 32;                      // this wave's n-quarter = windows w0win..w0win+31
  Win cur = load_win(w0win);
  for (int i = 0; i < 32; ++i) {
    Win nxt = load_win(w0win + (i < 31 ? i + 1 : 31));  // depth-1 prefetch

    f32x4 e00 = mfma16(cur.qf0, kf0, f32x4{0.f, 0.f, 0.f, 0.f});
    f32x4 e01 = mfma16(cur.qf1, kf0, f32x4{0.f, 0.f, 0.f, 0.f});
    f32x4 e10 = mfma16(cur.qf0, kf1, f32x4{0.f, 0.f, 0.f, 0.f});
    f32x4 e11 = mfma16(cur.qf1, kf1, f32x4{0.f, 0.f, 0.f, 0.f});

    float p00[4], p01[4], p10[4], p11[4];
    #pragma unroll
    for (int r = 0; r < 4; ++r) {
      p00[r] = __builtin_amdgcn_exp2f(fmaf(cur.qs0[r], -ks0, fmaf(e00[r], L2E, -cur.rm0[r])));
      p01[r] = __builtin_amdgcn_exp2f(fmaf(cur.qs1[r], -ks0, fmaf(e01[r], L2E, -cur.rm1[r])));
      p10[r] = __builtin_amdgcn_exp2f(fmaf(cur.qs0[r], -ks1, fmaf(e10[r], L2E, -cur.rm0[r])));
      p11[r] = __builtin_amdgcn_exp2f(fmaf(cur.qs1[r], -ks1, fmaf(e11[r], L2E, -cur.rm1[r])));
    }
    cs0 += ((p00[0] + p00[1]) + (p00[2] + p00[3])) + ((p01[0] + p01[1]) + (p01[2] + p01[3]));
    cs1 += ((p10[0] + p10[1]) + (p10[2] + p10[3])) + ((p11[0] + p11[1]) + (p11[2] + p11[3]));

    U16x8 pb0, pb1;   // B-frag k-slots (permuted layout matches xvp storage)
    #pragma unroll
    for (int r = 0; r < 4; ++r) {
      pb0.h[r] = (__bf16)p00[r]; pb0.h[4 + r] = (__bf16)p01[r];
      pb1.h[r] = (__bf16)p10[r]; pb1.h[4 + r] = (__bf16)p11[r];
    }

    U16x8 v0, v1, v2, v3;
    v0.q = cur.vq0; v1.q = cur.vq1; v2.q = cur.vq2; v3.q = cur.vq3;
    acc0[0] = mfma16(v0.v, pb0.v, acc0[0]);
    acc1[0] = mfma16(v0.v, pb1.v, acc1[0]);
    acc0[1] = mfma16(v1.v, pb0.v, acc0[1]);
    acc1[1] = mfma16(v1.v, pb1.v, acc1[1]);
    acc0[2] = mfma16(v2.v, pb0.v, acc0[2]);
    acc1[2] = mfma16(v2.v, pb1.v, acc1[2]);
    acc0[3] = mfma16(v3.v, pb0.v, acc0[3]);
    acc1[3] = mfma16(v3.v, pb1.v, acc1[3]);

    cur = nxt;
  }

  // per-wave colsum partials: lane lr holds m=m0(+16)+lr after lg-reduce
  cs0 += __shfl_xor(cs0, 16); cs0 += __shfl_xor(cs0, 32);
  cs1 += __shfl_xor(cs1, 16); cs1 += __shfl_xor(cs1, 32);
  if (lg == 0) { csl[w][lr] = cs0; csl[w][16 + lr] = cs1; }

  // cross-wave acc reduce (3 barriers, race-free)
  if (w >= 2) {
    #pragma unroll
    for (int ct = 0; ct < 4; ++ct) {
      *(f32x4*)&accl[w - 2][ct][l * 4]     = acc0[ct];
      *(f32x4*)&accl[w - 2][4 + ct][l * 4] = acc1[ct];
    }
  }
  __syncthreads();
  if (w < 2) {
    #pragma unroll
    for (int ct = 0; ct < 4; ++ct) {
      acc0[ct] += *(const f32x4*)&accl[w][ct][l * 4];
      acc1[ct] += *(const f32x4*)&accl[w][4 + ct][l * 4];
    }
  }
  __syncthreads();
  if (w == 1) {
    #pragma unroll
    for (int ct = 0; ct < 4; ++ct) {
      *(f32x4*)&accl[0][ct][l * 4]     = acc0[ct];
      *(f32x4*)&accl[0][4 + ct][l * 4] = acc1[ct];
    }
  }
  __syncthreads();
  if (w == 0) {
    #pragma unroll
    for (int ct = 0; ct < 4; ++ct) {
      acc0[ct] += *(const f32x4*)&accl[0][ct][l * 4];
      acc1[ct] += *(const f32x4*)&accl[0][4 + ct][l * 4];
    }
    float inv0 = __builtin_amdgcn_rcpf(1e-9f + csl[0][lr] + csl[1][lr] + csl[2][lr] + csl[3][lr]);
    float inv1 = __builtin_amdgcn_rcpf(1e-9f + csl[0][16 + lr] + csl[1][16 + lr] + csl[2][16 + lr] + csl[3][16 + lr]);

    // epilogue: diff = x - acc*inv, bf16 [b][n][c]; lane (lr,lg): m=m0(+16)+lr, c=c0+ct*16+lg*4+r
    #pragma unroll
    for (int ct = 0; ct < 4; ++ct) {
      {
        size_t base = ((size_t)(bN + m0 + lr)) * C_ + c0 + ct * 16 + lg * 4;
        uint2 xv2 = *(const uint2*)(xt + base);
        BF2 xa, xb; xa.w = xv2.x; xb.w = xv2.y;
        BF2 o0, o1;
        o0.h[0] = (__bf16)((float)xa.h[0] - acc0[ct][0] * inv0);
        o0.h[1] = (__bf16)((float)xa.h[1] - acc0[ct][1] * inv0);
        o1.h[0] = (__bf16)((float)xb.h[0] - acc0[ct][2] * inv0);
        o1.h[1] = (__bf16)((float)xb.h[1] - acc0[ct][3] * inv0);
        uint2 ov; ov.x = o0.w; ov.y = o1.w;
        *(uint2*)(diffb + base) = ov;
      }
      {
        size_t base = ((size_t)(bN + m0 + 16 + lr)) * C_ + c0 + ct * 16 + lg * 4;
        uint2 xv2 = *(const uint2*)(xt + base);
        BF2 xa, xb; xa.w = xv2.x; xb.w = xv2.y;
        BF2 o0, o1;
        o0.h[0] = (__bf16)((float)xa.h[0] - acc1[ct][0] * inv1);
        o0.h[1] = (__bf16)((float)xa.h[1] - acc1[ct][1] * inv1);
        o1.h[0] = (__bf16)((float)xb.h[0] - acc1[ct][2] * inv1);
        o1.h[1] = (__bf16)((float)xb.h[1] - acc1[ct][3] * inv1);
        uint2 ov; ov.x = o0.w; ov.y = o1.w;
        *(uint2*)(diffb + base) = ov;
      }
    }
  }
}

// ---------------- launch ----------------
extern "C" void kernel_launch(void* const* d_in, const int* in_sizes, int n_in,
                              void* d_out, int out_size, void* d_ws, size_t ws_size,
                              hipStream_t stream) {
  const float* x       = (const float*)d_in[0];
  const float* qk_w    = (const float*)d_in[1];
  const float* v_w     = (const float*)d_in[2];
  const float* v_b     = (const float*)d_in[3];
  const float* trans_w = (const float*)d_in[4];
  const float* trans_b = (const float*)d_in[5];
  const float* bn1s = (const float*)d_in[6];
  const float* bn1b = (const float*)d_in[7];
  const float* bn2s = (const float*)d_in[8];
  const float* bn2b = (const float*)d_in[9];
  const float* bn3s = (const float*)d_in[10];
  const float* bn3b = (const float*)d_in[11];
  const float* ans  = (const float*)d_in[12];
  const float* anb  = (const float*)d_in[13];
  float* out = (float*)d_out;
  char* ws = (char*)d_ws;

  if (ws_size < 27820032) return;

  u16*   xt    = (u16*)(ws + 0);          // [B][N][C] bf16   8 MB
  u16*   xvp   = (u16*)(ws + 8388608);    // [B][C][N'] bf16  8 MB (k-slot permuted)
  u16*   diffb = (u16*)(ws + 16777216);   // [B][N][C] bf16   8 MB
  u16*   qb    = (u16*)(ws + 25165824);   // [B][N][32] bf16  1 MB
  u16*   kb    = (u16*)(ws + 26214400);   // [B][N][32] bf16  1 MB
  u16*   wv    = (u16*)(ws + 27262976);
  u16*   wt    = (u16*)(ws + 27394048);
  float* wqkt  = (float*)(ws + 27525120);
  float* qsg   = (float*)(ws + 27557888);
  float* ksg   = (float*)(ws + 27623424);
  float* rmg   = (float*)(ws + 27688960);

  k_prep<<<64, 256, 0, stream>>>(v_w, trans_w, qk_w, wv, wt, wqkt);
  k_xt<<<1024, 256, 0, stream>>>(x, xt);
  k_qk<<<256, 256, 0, stream>>>(x, wqkt, bn1s, bn1b, bn2s, bn2b, qb, kb, qsg, ksg);
  k_gemm256<0><<<512, 256, 0, stream>>>(wv, xt, v_b, bn3s, bn3b, nullptr, xvp, nullptr);
  k_phaseA<<<512, 512, 0, stream>>>(qb, kb, qsg, ksg, rmg);
  k_phaseB<<<2048, 256, 0, stream>>>(qb, kb, qsg, ksg, rmg, xvp, xt, diffb);
  k_gemm256<1><<<512, 256, 0, stream>>>(wt, diffb, trans_b, ans, anb, x, nullptr, out);
}

// Round 6
// 261.044 us; speedup vs baseline: 4.1996x; 4.1996x over previous
//
#include <hip/hip_runtime.h>
#include <stdint.h>

#define B_ 4
#define C_ 256
#define N_ 4096
#define L2E 1.4426950408889634f

typedef unsigned short u16;
typedef unsigned int u32;
typedef float f32x4 __attribute__((ext_vector_type(4)));
typedef __bf16 bf16x8 __attribute__((ext_vector_type(8)));

union U16x8 { uint4 q; bf16x8 v; u16 u[8]; __bf16 h[8]; };
union BF2 { u32 w; __bf16 h[2]; };

__device__ __forceinline__ bf16x8 ld_bf8(const u16* p) {
  U16x8 t; t.q = *(const uint4*)p; return t.v;
}
__device__ __forceinline__ f32x4 mfma16(bf16x8 a, bf16x8 b, f32x4 c) {
  return __builtin_amdgcn_mfma_f32_16x16x32_bf16(a, b, c, 0, 0, 0);
}

// ---------------- K-prep: weight conversions ----------------
__global__ __launch_bounds__(256) void k_prep(const float* __restrict__ vw, const float* __restrict__ tw,
                                              const float* __restrict__ qkw,
                                              u16* __restrict__ wv, u16* __restrict__ wt, float* __restrict__ wqkt) {
  int i = blockIdx.x * 256 + threadIdx.x;
  int stride = gridDim.x * 256;
  for (int idx = i; idx < C_ * C_; idx += stride) {
    BF2 a, b; a.h[0] = (__bf16)vw[idx]; b.h[0] = (__bf16)tw[idx];
    wv[idx] = (u16)(a.w & 0xFFFF);
    wt[idx] = (u16)(b.w & 0xFFFF);
  }
  for (int idx = i; idx < 32 * C_; idx += stride) {
    int c = idx >> 8, cin = idx & 255;
    wqkt[cin * 32 + c] = qkw[idx];           // transposed, fp32 (exponent-accuracy path)
  }
}

// ---------------- K-xt: x [b][c][n] fp32 -> x_t [b][n][c] bf16 ----------------
__global__ __launch_bounds__(256) void k_xt(const float* __restrict__ x, u16* __restrict__ xt) {
  int bid = blockIdx.x;
  int cb = bid & 3, nt = (bid >> 2) & 63, b = bid >> 8;
  __shared__ u16 tile[64][66];
  int t = threadIdx.x, nl = t & 63, cg = t >> 6;
  const float* xp = x + ((size_t)b * C_ + cb * 64) * N_ + nt * 64;
  #pragma unroll
  for (int cc = 0; cc < 16; ++cc) {
    int c = cg * 16 + cc;
    BF2 v; v.h[0] = (__bf16)xp[(size_t)c * N_ + nl];
    tile[c][nl] = (u16)(v.w & 0xFFFF);
  }
  __syncthreads();
  u16* op = xt + ((size_t)b * N_ + nt * 64) * C_ + cb * 64;
  #pragma unroll
  for (int nn = 0; nn < 16; ++nn) {
    int n2 = cg * 16 + nn;
    op[(size_t)n2 * C_ + nl] = tile[nl][n2];
  }
}

// ---------------- K-qk: fp32 GEMM + bn1/bn2 + relu -> q',k' bf16 [b][n][32] ----------------
// qsg = (sum_c q) * log2(e)  [scaled domain for exp2]; ksg = sum_c k (raw).
__global__ __launch_bounds__(256) void k_qk(
    const float* __restrict__ x, const float* __restrict__ wqkt,
    const float* __restrict__ bn1s, const float* __restrict__ bn1b,
    const float* __restrict__ bn2s, const float* __restrict__ bn2b,
    u16* __restrict__ qb, u16* __restrict__ kb,
    float* __restrict__ qsg, float* __restrict__ ksg) {
  int bid = blockIdx.x;
  bid = (bid & 7) * 32 + (bid >> 3);
  int nt = bid & 63, b = bid >> 6;
  int t = threadIdx.x;
  int nl = t & 63;
  int qg = __builtin_amdgcn_readfirstlane(t >> 6);
  int n = nt * 64 + nl;

  __shared__ float red[4][64][33];
  __shared__ float qsum[4][64], ksum[4][64];

  float acc[32];
  #pragma unroll
  for (int c = 0; c < 32; ++c) acc[c] = 0.f;

  const float* xp = x + ((size_t)b * C_ + qg * 64) * N_ + n;
  const float* wp = wqkt + qg * 64 * 32;
  for (int i = 0; i < 64; ++i) {
    float xvv = xp[(size_t)i * N_];
    const float* wr = wp + i * 32;
    #pragma unroll
    for (int c = 0; c < 32; ++c) acc[c] = fmaf(wr[c], xvv, acc[c]);
  }
  #pragma unroll
  for (int c = 0; c < 32; ++c) red[qg][nl][c] = acc[c];
  __syncthreads();

  float pqs = 0.f, pks = 0.f;
  U16x8 tq, tk;
  #pragma unroll
  for (int i2 = 0; i2 < 8; ++i2) {
    int c = qg * 8 + i2;
    float s = red[0][nl][c] + red[1][nl][c] + red[2][nl][c] + red[3][nl][c];
    float fq = fmaxf(fmaf(s, bn1s[c], bn1b[c]), 0.f);
    float fk = fmaxf(fmaf(s, bn2s[c], bn2b[c]), 0.f);
    pqs += fq; pks += fk;
    tq.h[i2] = (__bf16)fq; tk.h[i2] = (__bf16)fk;
  }
  size_t ofs = ((size_t)(b * N_ + n)) * 32 + qg * 8;
  *(uint4*)(qb + ofs) = tq.q;
  *(uint4*)(kb + ofs) = tk.q;

  qsum[qg][nl] = pqs; ksum[qg][nl] = pks;
  __syncthreads();
  if (t < 64) {
    int nn2 = nt * 64 + t;
    qsg[b * N_ + nn2] = (qsum[0][t] + qsum[1][t] + qsum[2][t] + qsum[3][t]) * L2E;
    ksg[b * N_ + nn2] = ksum[0][t] + ksum[1][t] + ksum[2][t] + ksum[3][t];
  }
}

// ---------------- K-gemm256: out[o][n] = epilogue(W[256x256] @ act^T) ----------------
// MODE 0: v-conv -> x_v bf16 [b][c][n'] with n' k-slot-permuted within each 32-block
//         (n = s*16+g*4+t -> n' = g*8+s*4+t) so phaseB's PV A-fragment is one 16B load.
// MODE 1: trans-conv + residual -> out fp32
template<int MODE>
__global__ __launch_bounds__(256) void k_gemm256(
    const u16* __restrict__ W, const u16* __restrict__ act,
    const float* __restrict__ bias, const float* __restrict__ bns, const float* __restrict__ bnb,
    const float* __restrict__ xres, u16* __restrict__ outb, float* __restrict__ outf) {
  int bid = blockIdx.x;
  bid = (bid & 7) * 64 + (bid >> 3);
  int nt = bid & 127, b = bid >> 7;
  int n0 = nt * 32;
  int t = threadIdx.x;
  int w = t >> 6, l = t & 63, lr = l & 15, lg = l >> 4;

  f32x4 acc[4][2];
  #pragma unroll
  for (int ot = 0; ot < 4; ++ot)
    #pragma unroll
    for (int ns = 0; ns < 2; ++ns) acc[ot][ns] = f32x4{0.f, 0.f, 0.f, 0.f};

  const u16* actp = act + ((size_t)b * N_ + n0) * C_;
  for (int kk = 0; kk < 8; ++kk) {
    int k0 = kk * 32;
    bf16x8 bf[2];
    #pragma unroll
    for (int ns = 0; ns < 2; ++ns)
      bf[ns] = ld_bf8(actp + (size_t)(ns * 16 + lr) * C_ + k0 + lg * 8);
    #pragma unroll
    for (int ot = 0; ot < 4; ++ot) {
      bf16x8 af = ld_bf8(W + (size_t)(w * 64 + ot * 16 + lr) * C_ + k0 + lg * 8);
      #pragma unroll
      for (int ns = 0; ns < 2; ++ns) acc[ot][ns] = mfma16(af, bf[ns], acc[ot][ns]);
    }
  }
  #pragma unroll
  for (int ot = 0; ot < 4; ++ot) {
    #pragma unroll
    for (int r = 0; r < 4; ++r) {
      int oc = w * 64 + ot * 16 + lg * 4 + r;
      float sO = bns[oc], bO = bnb[oc], biO = bias[oc];
      #pragma unroll
      for (int ns = 0; ns < 2; ++ns) {
        int nn = ns * 16 + lr;
        float val = fmaxf(fmaf(acc[ot][ns][r] + biO, sO, bO), 0.f);
        if (MODE == 0) {
          int np = ((nn >> 2) & 3) * 8 + (nn >> 4) * 4 + (nn & 3);   // k-slot permute
          size_t idx = ((size_t)b * C_ + oc) * N_ + n0 + np;
          BF2 v; v.h[0] = (__bf16)val; outb[idx] = (u16)(v.w & 0xFFFF);
        } else {
          size_t idx = ((size_t)b * C_ + oc) * N_ + n0 + nn;
          outf[idx] = xres[idx] + val;
        }
      }
    }
  }
}

// ---------------- K-phaseA: fused row stat rmg = max' + log2(sum') (scaled domain) ----------------
__global__ __launch_bounds__(512) void k_phaseA(
    const u16* __restrict__ qb, const u16* __restrict__ kb,
    const float* __restrict__ qsg, const float* __restrict__ ksg,
    float* __restrict__ rmg) {
  int bid = blockIdx.x;
  bid = (bid & 7) * 64 + (bid >> 3);
  int nt = bid & 127, b = bid >> 7;
  int bN = b * N_;
  int t = threadIdx.x;
  int w = t >> 6, l = t & 63, lr = l & 15, lg = l >> 4;
  int nsub = w & 1, mq = w >> 1;
  int nrow0 = nt * 32 + nsub * 16;

  __shared__ float pM[4][32], pS[4][32];

  bf16x8 qf = ld_bf8(qb + ((size_t)(bN + nrow0 + lr)) * 32 + lg * 8);
  f32x4 qsv = *(const f32x4*)(qsg + bN + nrow0 + lg * 4);   // already *L2E

  float Mv[4], Sv[4];
  #pragma unroll
  for (int r = 0; r < 4; ++r) { Mv[r] = -3e38f; Sv[r] = 0.f; }

  int mbase = mq * 1024;
  for (int ms = 0; ms < 16; ++ms) {
    float ev[4][4];
    #pragma unroll
    for (int mt2 = 0; mt2 < 4; ++mt2) {
      int m0 = mbase + ms * 64 + mt2 * 16;
      bf16x8 kf = ld_bf8(kb + ((size_t)(bN + m0 + lr)) * 32 + lg * 8);
      f32x4 e = mfma16(qf, kf, f32x4{0.f, 0.f, 0.f, 0.f});
      float ksv = ksg[bN + m0 + lr];
      #pragma unroll
      for (int r = 0; r < 4; ++r) ev[mt2][r] = fmaf(e[r], L2E, -qsv[r] * ksv);  // scaled e'
    }
    #pragma unroll
    for (int r = 0; r < 4; ++r) {
      float t0 = fmaxf(fmaxf(ev[0][r], ev[1][r]), fmaxf(ev[2][r], ev[3][r]));
      float Mn = fmaxf(Mv[r], t0);
      Sv[r] = Sv[r] * __builtin_amdgcn_exp2f(Mv[r] - Mn)
            + __builtin_amdgcn_exp2f(ev[0][r] - Mn)
            + __builtin_amdgcn_exp2f(ev[1][r] - Mn)
            + __builtin_amdgcn_exp2f(ev[2][r] - Mn)
            + __builtin_amdgcn_exp2f(ev[3][r] - Mn);
      Mv[r] = Mn;
    }
  }
  #pragma unroll
  for (int off = 1; off < 16; off <<= 1) {
    #pragma unroll
    for (int r = 0; r < 4; ++r) {
      float Mo = __shfl_xor(Mv[r], off);
      float So = __shfl_xor(Sv[r], off);
      float Mn = fmaxf(Mv[r], Mo);
      Sv[r] = Sv[r] * __builtin_amdgcn_exp2f(Mv[r] - Mn)
            + So   * __builtin_amdgcn_exp2f(Mo   - Mn);
      Mv[r] = Mn;
    }
  }
  if (lr == 0) {
    #pragma unroll
    for (int r = 0; r < 4; ++r) {
      pM[mq][nsub * 16 + lg * 4 + r] = Mv[r];
      pS[mq][nsub * 16 + lg * 4 + r] = Sv[r];
    }
  }
  __syncthreads();
  if (t < 32) {
    float M = fmaxf(fmaxf(pM[0][t], pM[1][t]), fmaxf(pM[2][t], pM[3][t]));
    float S = pS[0][t] * __builtin_amdgcn_exp2f(pM[0][t] - M)
            + pS[1][t] * __builtin_amdgcn_exp2f(pM[1][t] - M)
            + pS[2][t] * __builtin_amdgcn_exp2f(pM[2][t] - M)
            + pS[3][t] * __builtin_amdgcn_exp2f(pM[3][t] - M);
    rmg[bN + nt * 32 + t] = M + __builtin_amdgcn_logf(S);   // v_log_f32 = log2
  }
}

// ---------------- K-phaseB: barrier-free flash PV, 8 waves = (c-quarter, n-half) ----------------
// 512 blocks (b, mt128) x 512 thr = 2 blocks/CU = 16 waves/CU = 4 waves/SIMD.
// launch_bounds(512,4): VGPR cap 128, body needs ~80 (round-3 footprint) -> NO SPILL.
// Wave (cq, nh): m32 x c64 over n-half nh. Colsum via ones-MFMA (matrix pipe, not VALU).
// One barrier at the end: nh=1 waves dump acc to LDS, nh=0 waves add + epilogue.
struct Win {
  bf16x8 qf0, qf1;
  f32x4 qs0, qs1, rm0, rm1;
  uint4 vq0, vq1, vq2, vq3;
};

__global__ __launch_bounds__(512, 4) void k_phaseB(
    const u16* __restrict__ qb, const u16* __restrict__ kb,
    const float* __restrict__ qsg, const float* __restrict__ ksg,
    const float* __restrict__ rmg,
    const u16* __restrict__ xvp, const u16* __restrict__ xt,
    u16* __restrict__ diffb) {
  int bid = blockIdx.x;
  bid = (bid & 7) * 64 + (bid >> 3);       // XCD swizzle (512 wgs, bijective)
  int mt = bid & 127, b = bid >> 7;
  int m0 = mt * 32;
  int bN = b * N_;
  int t = threadIdx.x;
  int w = t >> 6, l = t & 63, lr = l & 15, lg = l >> 4;
  int cq = w & 3, nh = w >> 2;
  int c0 = cq * 64;

  __shared__ float accl[4][2048];          // nh=1 partials: [cq][(ct*2+msub)*256 + l*4]
  __shared__ float csl[8][32];

  bf16x8 kf0 = ld_bf8(kb + (size_t)(bN + m0 + lr) * 32 + lg * 8);
  bf16x8 kf1 = ld_bf8(kb + (size_t)(bN + m0 + 16 + lr) * 32 + lg * 8);
  float ks0 = ksg[bN + m0 + lr];
  float ks1 = ksg[bN + m0 + 16 + lr];

  U16x8 onesu;
  #pragma unroll
  for (int i = 0; i < 8; ++i) onesu.u[i] = 0x3F80;   // bf16 1.0
  bf16x8 ones = onesu.v;

  const u16* qbase = qb + (size_t)bN * 32;
  const float* qsb = qsg + bN;
  const float* rmb = rmg + bN;
  const u16* vbase = xvp + (size_t)(b * C_ + c0) * N_ + (size_t)lr * N_;

  f32x4 acc0[4], acc1[4];
  #pragma unroll
  for (int ct = 0; ct < 4; ++ct) {
    acc0[ct] = f32x4{0.f, 0.f, 0.f, 0.f};
    acc1[ct] = f32x4{0.f, 0.f, 0.f, 0.f};
  }
  f32x4 accs0 = f32x4{0.f, 0.f, 0.f, 0.f};
  f32x4 accs1 = f32x4{0.f, 0.f, 0.f, 0.f};

  auto load_win = [&](int wd) {
    Win W;
    int nb = wd * 32;
    W.qf0 = ld_bf8(qbase + (size_t)(nb + lr) * 32 + lg * 8);
    W.qf1 = ld_bf8(qbase + (size_t)(nb + 16 + lr) * 32 + lg * 8);
    W.qs0 = *(const f32x4*)(qsb + nb + lg * 4);
    W.qs1 = *(const f32x4*)(qsb + nb + 16 + lg * 4);
    W.rm0 = *(const f32x4*)(rmb + nb + lg * 4);
    W.rm1 = *(const f32x4*)(rmb + nb + 16 + lg * 4);
    const u16* vp = vbase + nb + lg * 8;
    W.vq0 = *(const uint4*)(vp);
    W.vq1 = *(const uint4*)(vp + (size_t)16 * N_);
    W.vq2 = *(const uint4*)(vp + (size_t)32 * N_);
    W.vq3 = *(const uint4*)(vp + (size_t)48 * N_);
    return W;
  };

  int wbase = nh * 64;                     // this wave's n-half = windows wbase..wbase+63
  Win cur = load_win(wbase);
  for (int i = 0; i < 64; ++i) {
    Win nxt = load_win(wbase + (i < 63 ? i + 1 : 63));  // depth-1 prefetch

    f32x4 e00 = mfma16(cur.qf0, kf0, f32x4{0.f, 0.f, 0.f, 0.f});
    f32x4 e01 = mfma16(cur.qf1, kf0, f32x4{0.f, 0.f, 0.f, 0.f});
    f32x4 e10 = mfma16(cur.qf0, kf1, f32x4{0.f, 0.f, 0.f, 0.f});
    f32x4 e11 = mfma16(cur.qf1, kf1, f32x4{0.f, 0.f, 0.f, 0.f});

    float p00[4], p01[4], p10[4], p11[4];
    #pragma unroll
    for (int r = 0; r < 4; ++r) {
      p00[r] = __builtin_amdgcn_exp2f(fmaf(cur.qs0[r], -ks0, fmaf(e00[r], L2E, -cur.rm0[r])));
      p01[r] = __builtin_amdgcn_exp2f(fmaf(cur.qs1[r], -ks0, fmaf(e01[r], L2E, -cur.rm1[r])));
      p10[r] = __builtin_amdgcn_exp2f(fmaf(cur.qs0[r], -ks1, fmaf(e10[r], L2E, -cur.rm0[r])));
      p11[r] = __builtin_amdgcn_exp2f(fmaf(cur.qs1[r], -ks1, fmaf(e11[r], L2E, -cur.rm1[r])));
    }

    U16x8 pb0, pb1;   // B-frag k-slots (permuted layout matches xvp storage)
    #pragma unroll
    for (int r = 0; r < 4; ++r) {
      pb0.h[r] = (__bf16)p00[r]; pb0.h[4 + r] = (__bf16)p01[r];
      pb1.h[r] = (__bf16)p10[r]; pb1.h[4 + r] = (__bf16)p11[r];
    }

    // colsum on the matrix pipe: rows of ones -> every reg = window-colsum for m=lr
    accs0 = mfma16(ones, pb0.v, accs0);
    accs1 = mfma16(ones, pb1.v, accs1);

    U16x8 v0, v1, v2, v3;
    v0.q = cur.vq0; v1.q = cur.vq1; v2.q = cur.vq2; v3.q = cur.vq3;
    acc0[0] = mfma16(v0.v, pb0.v, acc0[0]);
    acc1[0] = mfma16(v0.v, pb1.v, acc1[0]);
    acc0[1] = mfma16(v1.v, pb0.v, acc0[1]);
    acc1[1] = mfma16(v1.v, pb1.v, acc1[1]);
    acc0[2] = mfma16(v2.v, pb0.v, acc0[2]);
    acc1[2] = mfma16(v2.v, pb1.v, acc1[2]);
    acc0[3] = mfma16(v3.v, pb0.v, acc0[3]);
    acc1[3] = mfma16(v3.v, pb1.v, acc1[3]);

    cur = nxt;
  }

  // publish: colsum partials (identical across lg -> write lg==0 only) + nh=1 acc
  if (lg == 0) { csl[w][lr] = accs0[0]; csl[w][16 + lr] = accs1[0]; }
  if (nh == 1) {
    #pragma unroll
    for (int ct = 0; ct < 4; ++ct) {
      *(f32x4*)&accl[cq][(ct * 2 + 0) * 256 + l * 4] = acc0[ct];
      *(f32x4*)&accl[cq][(ct * 2 + 1) * 256 + l * 4] = acc1[ct];
    }
  }
  __syncthreads();
  if (nh == 0) {
    #pragma unroll
    for (int ct = 0; ct < 4; ++ct) {
      acc0[ct] += *(const f32x4*)&accl[cq][(ct * 2 + 0) * 256 + l * 4];
      acc1[ct] += *(const f32x4*)&accl[cq][(ct * 2 + 1) * 256 + l * 4];
    }
    float inv0 = __builtin_amdgcn_rcpf(1e-9f + csl[cq][lr] + csl[cq + 4][lr]);
    float inv1 = __builtin_amdgcn_rcpf(1e-9f + csl[cq][16 + lr] + csl[cq + 4][16 + lr]);

    // epilogue: diff = x - acc*inv, bf16 [b][n][c]; lane (lr,lg): m=m0(+16)+lr, c=c0+ct*16+lg*4+r
    #pragma unroll
    for (int ct = 0; ct < 4; ++ct) {
      {
        size_t base = ((size_t)(bN + m0 + lr)) * C_ + c0 + ct * 16 + lg * 4;
        uint2 xv2 = *(const uint2*)(xt + base);
        BF2 xa, xb; xa.w = xv2.x; xb.w = xv2.y;
        BF2 o0, o1;
        o0.h[0] = (__bf16)((float)xa.h[0] - acc0[ct][0] * inv0);
        o0.h[1] = (__bf16)((float)xa.h[1] - acc0[ct][1] * inv0);
        o1.h[0] = (__bf16)((float)xb.h[0] - acc0[ct][2] * inv0);
        o1.h[1] = (__bf16)((float)xb.h[1] - acc0[ct][3] * inv0);
        uint2 ov; ov.x = o0.w; ov.y = o1.w;
        *(uint2*)(diffb + base) = ov;
      }
      {
        size_t base = ((size_t)(bN + m0 + 16 + lr)) * C_ + c0 + ct * 16 + lg * 4;
        uint2 xv2 = *(const uint2*)(xt + base);
        BF2 xa, xb; xa.w = xv2.x; xb.w = xv2.y;
        BF2 o0, o1;
        o0.h[0] = (__bf16)((float)xa.h[0] - acc1[ct][0] * inv1);
        o0.h[1] = (__bf16)((float)xa.h[1] - acc1[ct][1] * inv1);
        o1.h[0] = (__bf16)((float)xb.h[0] - acc1[ct][2] * inv1);
        o1.h[1] = (__bf16)((float)xb.h[1] - acc1[ct][3] * inv1);
        uint2 ov; ov.x = o0.w; ov.y = o1.w;
        *(uint2*)(diffb + base) = ov;
      }
    }
  }
}

// ---------------- launch ----------------
extern "C" void kernel_launch(void* const* d_in, const int* in_sizes, int n_in,
                              void* d_out, int out_size, void* d_ws, size_t ws_size,
                              hipStream_t stream) {
  const float* x       = (const float*)d_in[0];
  const float* qk_w    = (const float*)d_in[1];
  const float* v_w     = (const float*)d_in[2];
  const float* v_b     = (const float*)d_in[3];
  const float* trans_w = (const float*)d_in[4];
  const float* trans_b = (const float*)d_in[5];
  const float* bn1s = (const float*)d_in[6];
  const float* bn1b = (const float*)d_in[7];
  const float* bn2s = (const float*)d_in[8];
  const float* bn2b = (const float*)d_in[9];
  const float* bn3s = (const float*)d_in[10];
  const float* bn3b = (const float*)d_in[11];
  const float* ans  = (const float*)d_in[12];
  const float* anb  = (const float*)d_in[13];
  float* out = (float*)d_out;
  char* ws = (char*)d_ws;

  if (ws_size < 27820032) return;

  u16*   xt    = (u16*)(ws + 0);          // [B][N][C] bf16   8 MB
  u16*   xvp   = (u16*)(ws + 8388608);    // [B][C][N'] bf16  8 MB (k-slot permuted)
  u16*   diffb = (u16*)(ws + 16777216);   // [B][N][C] bf16   8 MB
  u16*   qb    = (u16*)(ws + 25165824);   // [B][N][32] bf16  1 MB
  u16*   kb    = (u16*)(ws + 26214400);   // [B][N][32] bf16  1 MB
  u16*   wv    = (u16*)(ws + 27262976);
  u16*   wt    = (u16*)(ws + 27394048);
  float* wqkt  = (float*)(ws + 27525120);
  float* qsg   = (float*)(ws + 27557888);
  float* ksg   = (float*)(ws + 27623424);
  float* rmg   = (float*)(ws + 27688960);

  k_prep<<<64, 256, 0, stream>>>(v_w, trans_w, qk_w, wv, wt, wqkt);
  k_xt<<<1024, 256, 0, stream>>>(x, xt);
  k_qk<<<256, 256, 0, stream>>>(x, wqkt, bn1s, bn1b, bn2s, bn2b, qb, kb, qsg, ksg);
  k_gemm256<0><<<512, 256, 0, stream>>>(wv, xt, v_b, bn3s, bn3b, nullptr, xvp, nullptr);
  k_phaseA<<<512, 512, 0, stream>>>(qb, kb, qsg, ksg, rmg);
  k_phaseB<<<512, 512, 0, stream>>>(qb, kb, qsg, ksg, rmg, xvp, xt, diffb);
  k_gemm256<1><<<512, 256, 0, stream>>>(wt, diffb, trans_b, ans, anb, x, nullptr, out);
}

// Round 7
// 169.123 us; speedup vs baseline: 6.4822x; 1.5435x over previous
//
#include <hip/hip_runtime.h>
#include <stdint.h>

#define B_ 4
#define C_ 256
#define N_ 4096
#define L2E 1.4426950408889634f

typedef unsigned short u16;
typedef unsigned int u32;
typedef float f32x4 __attribute__((ext_vector_type(4)));
typedef __bf16 bf16x8 __attribute__((ext_vector_type(8)));

union U16x8 { uint4 q; bf16x8 v; u16 u[8]; __bf16 h[8]; };
union BF2 { u32 w; __bf16 h[2]; };

__device__ __forceinline__ bf16x8 ld_bf8(const u16* p) {
  U16x8 t; t.q = *(const uint4*)p; return t.v;
}
__device__ __forceinline__ f32x4 mfma16(bf16x8 a, bf16x8 b, f32x4 c) {
  return __builtin_amdgcn_mfma_f32_16x16x32_bf16(a, b, c, 0, 0, 0);
}

// Fragment-major layouts (all hot loads become ptr + lane*16B, 1 segment/instr):
//   qfm/kfm: [b][chunk16 = n>>4][lane64][8 u16]   (lane = (n&15) + kgroup*16)
//   vq:      [b][chunk32 = n>>5][cfrag = c>>4][lane64][8 u16]
//            element (c, kslot np): lane = (c&15) + (np>>3)*16, j = np&7

// ---------------- K-prep: weight conversions ----------------
__global__ __launch_bounds__(256) void k_prep(const float* __restrict__ vw, const float* __restrict__ tw,
                                              const float* __restrict__ qkw,
                                              u16* __restrict__ wv, u16* __restrict__ wt, float* __restrict__ wqkt) {
  int i = blockIdx.x * 256 + threadIdx.x;
  int stride = gridDim.x * 256;
  for (int idx = i; idx < C_ * C_; idx += stride) {
    BF2 a, b; a.h[0] = (__bf16)vw[idx]; b.h[0] = (__bf16)tw[idx];
    wv[idx] = (u16)(a.w & 0xFFFF);
    wt[idx] = (u16)(b.w & 0xFFFF);
  }
  for (int idx = i; idx < 32 * C_; idx += stride) {
    int c = idx >> 8, cin = idx & 255;
    wqkt[cin * 32 + c] = qkw[idx];           // transposed, fp32 (exponent-accuracy path)
  }
}

// ---------------- K-xt: x [b][c][n] fp32 -> x_t [b][n][c] bf16 ----------------
__global__ __launch_bounds__(256) void k_xt(const float* __restrict__ x, u16* __restrict__ xt) {
  int bid = blockIdx.x;
  int cb = bid & 3, nt = (bid >> 2) & 63, b = bid >> 8;
  __shared__ u16 tile[64][66];
  int t = threadIdx.x, nl = t & 63, cg = t >> 6;
  const float* xp = x + ((size_t)b * C_ + cb * 64) * N_ + nt * 64;
  #pragma unroll
  for (int cc = 0; cc < 16; ++cc) {
    int c = cg * 16 + cc;
    BF2 v; v.h[0] = (__bf16)xp[(size_t)c * N_ + nl];
    tile[c][nl] = (u16)(v.w & 0xFFFF);
  }
  __syncthreads();
  u16* op = xt + ((size_t)b * N_ + nt * 64) * C_ + cb * 64;
  #pragma unroll
  for (int nn = 0; nn < 16; ++nn) {
    int n2 = cg * 16 + nn;
    op[(size_t)n2 * C_ + nl] = tile[nl][n2];
  }
}

// ---------------- K-qk: fp32 GEMM + bn1/bn2 + relu -> q',k' fragment-major ----------------
// qsg = (sum_c q) * log2(e); ksg = sum_c k (raw).
__global__ __launch_bounds__(256) void k_qk(
    const float* __restrict__ x, const float* __restrict__ wqkt,
    const float* __restrict__ bn1s, const float* __restrict__ bn1b,
    const float* __restrict__ bn2s, const float* __restrict__ bn2b,
    u16* __restrict__ qfm, u16* __restrict__ kfm,
    float* __restrict__ qsg, float* __restrict__ ksg) {
  int bid = blockIdx.x;
  bid = (bid & 7) * 32 + (bid >> 3);
  int nt = bid & 63, b = bid >> 6;
  int t = threadIdx.x;
  int nl = t & 63;
  int qg = __builtin_amdgcn_readfirstlane(t >> 6);
  int n = nt * 64 + nl;

  __shared__ float red[4][64][33];
  __shared__ float qsum[4][64], ksum[4][64];

  float acc[32];
  #pragma unroll
  for (int c = 0; c < 32; ++c) acc[c] = 0.f;

  const float* xp = x + ((size_t)b * C_ + qg * 64) * N_ + n;
  const float* wp = wqkt + qg * 64 * 32;
  for (int i = 0; i < 64; ++i) {
    float xvv = xp[(size_t)i * N_];
    const float* wr = wp + i * 32;
    #pragma unroll
    for (int c = 0; c < 32; ++c) acc[c] = fmaf(wr[c], xvv, acc[c]);
  }
  #pragma unroll
  for (int c = 0; c < 32; ++c) red[qg][nl][c] = acc[c];
  __syncthreads();

  float pqs = 0.f, pks = 0.f;
  U16x8 tq, tk;
  #pragma unroll
  for (int i2 = 0; i2 < 8; ++i2) {
    int c = qg * 8 + i2;
    float s = red[0][nl][c] + red[1][nl][c] + red[2][nl][c] + red[3][nl][c];
    float fq = fmaxf(fmaf(s, bn1s[c], bn1b[c]), 0.f);
    float fk = fmaxf(fmaf(s, bn2s[c], bn2b[c]), 0.f);
    pqs += fq; pks += fk;
    tq.h[i2] = (__bf16)fq; tk.h[i2] = (__bf16)fk;
  }
  // fragment-major: chunk = n>>4, lane = (n&15) + qg*16
  size_t fbase = (((size_t)b * 256 + (n >> 4)) * 64 + (n & 15) + qg * 16) * 8;
  *(uint4*)(qfm + fbase) = tq.q;
  *(uint4*)(kfm + fbase) = tk.q;

  qsum[qg][nl] = pqs; ksum[qg][nl] = pks;
  __syncthreads();
  if (t < 64) {
    int nn2 = nt * 64 + t;
    qsg[b * N_ + nn2] = (qsum[0][t] + qsum[1][t] + qsum[2][t] + qsum[3][t]) * L2E;
    ksg[b * N_ + nn2] = ksum[0][t] + ksum[1][t] + ksum[2][t] + ksum[3][t];
  }
}

// ---------------- K-gemm256: out[o][n] = epilogue(W[256x256] @ act^T) ----------------
// MODE 0: v-conv -> vq fragment-major (LDS-coalesced dump)
// MODE 1: trans-conv + residual -> out fp32
template<int MODE>
__global__ __launch_bounds__(256) void k_gemm256(
    const u16* __restrict__ W, const u16* __restrict__ act,
    const float* __restrict__ bias, const float* __restrict__ bns, const float* __restrict__ bnb,
    const float* __restrict__ xres, u16* __restrict__ outb, float* __restrict__ outf) {
  int bid = blockIdx.x;
  bid = (bid & 7) * 64 + (bid >> 3);
  int nt = bid & 127, b = bid >> 7;
  int n0 = nt * 32;
  int t = threadIdx.x;
  int w = t >> 6, l = t & 63, lr = l & 15, lg = l >> 4;

  __shared__ u16 fbuf[16 * 512];             // MODE 0 only: 16 frags x 1KB

  f32x4 acc[4][2];
  #pragma unroll
  for (int ot = 0; ot < 4; ++ot)
    #pragma unroll
    for (int ns = 0; ns < 2; ++ns) acc[ot][ns] = f32x4{0.f, 0.f, 0.f, 0.f};

  const u16* actp = act + ((size_t)b * N_ + n0) * C_;
  for (int kk = 0; kk < 8; ++kk) {
    int k0 = kk * 32;
    bf16x8 bf[2];
    #pragma unroll
    for (int ns = 0; ns < 2; ++ns)
      bf[ns] = ld_bf8(actp + (size_t)(ns * 16 + lr) * C_ + k0 + lg * 8);
    #pragma unroll
    for (int ot = 0; ot < 4; ++ot) {
      bf16x8 af = ld_bf8(W + (size_t)(w * 64 + ot * 16 + lr) * C_ + k0 + lg * 8);
      #pragma unroll
      for (int ns = 0; ns < 2; ++ns) acc[ot][ns] = mfma16(af, bf[ns], acc[ot][ns]);
    }
  }
  #pragma unroll
  for (int ot = 0; ot < 4; ++ot) {
    #pragma unroll
    for (int r = 0; r < 4; ++r) {
      int oc = w * 64 + ot * 16 + lg * 4 + r;
      float sO = bns[oc], bO = bnb[oc], biO = bias[oc];
      #pragma unroll
      for (int ns = 0; ns < 2; ++ns) {
        float val = fmaxf(fmaf(acc[ot][ns][r] + biO, sO, bO), 0.f);
        if (MODE == 0) {
          // frag element (oc, np): np = (lr>>2)*8 + ns*4 + (lr&3)
          int u16off = (lg * 4 + r) * 8 + (lr >> 2) * 128 + ns * 4 + (lr & 3);
          BF2 v; v.h[0] = (__bf16)val;
          fbuf[(w * 4 + ot) * 512 + u16off] = (u16)(v.w & 0xFFFF);
        } else {
          int nn = ns * 16 + lr;
          size_t idx = ((size_t)b * C_ + oc) * N_ + n0 + nn;
          outf[idx] = xres[idx] + val;
        }
      }
    }
  }
  if (MODE == 0) {
    __syncthreads();
    #pragma unroll
    for (int rep = 0; rep < 4; ++rep) {
      int f = rep * 4 + (t >> 6);
      size_t dst = (((size_t)b * 128 + nt) * 16 + f) * 512 + (size_t)(t & 63) * 8;
      *(uint4*)(outb + dst) = *(const uint4*)&fbuf[f * 512 + (t & 63) * 8];
    }
  }
}

// ---------------- K-phaseA: fused row stat rmg = max' + log2(sum') ----------------
__global__ __launch_bounds__(512) void k_phaseA(
    const u16* __restrict__ qfm, const u16* __restrict__ kfm,
    const float* __restrict__ qsg, const float* __restrict__ ksg,
    float* __restrict__ rmg) {
  int bid = blockIdx.x;
  bid = (bid & 7) * 64 + (bid >> 3);
  int nt = bid & 127, b = bid >> 7;
  int bN = b * N_;
  int t = threadIdx.x;
  int w = t >> 6, l = t & 63, lr = l & 15, lg = l >> 4;
  int nsub = w & 1, mq = w >> 1;
  int nrow0 = nt * 32 + nsub * 16;

  __shared__ float pM[4][32], pS[4][32];

  const u16* qf_b = qfm + (size_t)b * 131072;
  const u16* kf_b = kfm + (size_t)b * 131072;

  bf16x8 qf = ld_bf8(qf_b + (size_t)(nrow0 >> 4) * 512 + l * 8);
  f32x4 qsv = *(const f32x4*)(qsg + bN + nrow0 + lg * 4);   // already *L2E

  float Mv[4], Sv[4];
  #pragma unroll
  for (int r = 0; r < 4; ++r) { Mv[r] = -3e38f; Sv[r] = 0.f; }

  int mbase = mq * 1024;
  for (int ms = 0; ms < 16; ++ms) {
    float ev[4][4];
    #pragma unroll
    for (int mt2 = 0; mt2 < 4; ++mt2) {
      int m0 = mbase + ms * 64 + mt2 * 16;
      bf16x8 kf = ld_bf8(kf_b + (size_t)(m0 >> 4) * 512 + l * 8);
      f32x4 e = mfma16(qf, kf, f32x4{0.f, 0.f, 0.f, 0.f});
      float ksv = ksg[bN + m0 + lr];
      #pragma unroll
      for (int r = 0; r < 4; ++r) ev[mt2][r] = fmaf(e[r], L2E, -qsv[r] * ksv);  // scaled e'
    }
    #pragma unroll
    for (int r = 0; r < 4; ++r) {
      float t0 = fmaxf(fmaxf(ev[0][r], ev[1][r]), fmaxf(ev[2][r], ev[3][r]));
      float Mn = fmaxf(Mv[r], t0);
      Sv[r] = Sv[r] * __builtin_amdgcn_exp2f(Mv[r] - Mn)
            + __builtin_amdgcn_exp2f(ev[0][r] - Mn)
            + __builtin_amdgcn_exp2f(ev[1][r] - Mn)
            + __builtin_amdgcn_exp2f(ev[2][r] - Mn)
            + __builtin_amdgcn_exp2f(ev[3][r] - Mn);
      Mv[r] = Mn;
    }
  }
  #pragma unroll
  for (int off = 1; off < 16; off <<= 1) {
    #pragma unroll
    for (int r = 0; r < 4; ++r) {
      float Mo = __shfl_xor(Mv[r], off);
      float So = __shfl_xor(Sv[r], off);
      float Mn = fmaxf(Mv[r], Mo);
      Sv[r] = Sv[r] * __builtin_amdgcn_exp2f(Mv[r] - Mn)
            + So   * __builtin_amdgcn_exp2f(Mo   - Mn);
      Mv[r] = Mn;
    }
  }
  if (lr == 0) {
    #pragma unroll
    for (int r = 0; r < 4; ++r) {
      pM[mq][nsub * 16 + lg * 4 + r] = Mv[r];
      pS[mq][nsub * 16 + lg * 4 + r] = Sv[r];
    }
  }
  __syncthreads();
  if (t < 32) {
    float M = fmaxf(fmaxf(pM[0][t], pM[1][t]), fmaxf(pM[2][t], pM[3][t]));
    float S = pS[0][t] * __builtin_amdgcn_exp2f(pM[0][t] - M)
            + pS[1][t] * __builtin_amdgcn_exp2f(pM[1][t] - M)
            + pS[2][t] * __builtin_amdgcn_exp2f(pM[2][t] - M)
            + pS[3][t] * __builtin_amdgcn_exp2f(pM[3][t] - M);
    rmg[bN + nt * 32 + t] = M + __builtin_amdgcn_logf(S);   // v_log_f32 = log2
  }
}

// ---------------- K-phaseB: round-6 structure, fragment-major (coalesced) loads ----------------
// 512 blocks (b, mt128) x 512 thr; 8 waves = (cq4, nh2); wave = m32 x c64 x n-half.
// Every hot-loop load is now ONE contiguous 1KB segment (was 16 x 64B).
struct Win {
  bf16x8 qf0, qf1;
  f32x4 qs0, qs1, rm0, rm1;
  uint4 vq0, vq1, vq2, vq3;
};

__global__ __launch_bounds__(512, 4) void k_phaseB(
    const u16* __restrict__ qfm, const u16* __restrict__ kfm,
    const float* __restrict__ qsg, const float* __restrict__ ksg,
    const float* __restrict__ rmg,
    const u16* __restrict__ vq, const u16* __restrict__ xt,
    u16* __restrict__ diffb) {
  int bid = blockIdx.x;
  bid = (bid & 7) * 64 + (bid >> 3);       // XCD swizzle (512 wgs, bijective)
  int mt = bid & 127, b = bid >> 7;
  int m0 = mt * 32;
  int bN = b * N_;
  int t = threadIdx.x;
  int w = t >> 6, l = t & 63, lr = l & 15, lg = l >> 4;
  int cq = w & 3, nh = w >> 2;
  int c0 = cq * 64;

  __shared__ float accl[4][2048];          // nh=1 partials
  __shared__ float csl[8][32];

  const u16* kf_b = kfm + (size_t)b * 131072;
  bf16x8 kf0 = ld_bf8(kf_b + (size_t)(mt * 2) * 512 + l * 8);
  bf16x8 kf1 = ld_bf8(kf_b + (size_t)(mt * 2 + 1) * 512 + l * 8);
  float ks0 = ksg[bN + m0 + lr];
  float ks1 = ksg[bN + m0 + 16 + lr];

  U16x8 onesu;
  #pragma unroll
  for (int i = 0; i < 8; ++i) onesu.u[i] = 0x3F80;   // bf16 1.0
  bf16x8 ones = onesu.v;

  const u16* qf_b = qfm + (size_t)b * 131072;
  const float* qsb = qsg + bN;
  const float* rmb = rmg + bN;
  const u16* vq_b = vq + (size_t)b * 1048576 + (size_t)(cq * 4) * 512 + (size_t)l * 8;

  f32x4 acc0[4], acc1[4];
  #pragma unroll
  for (int ct = 0; ct < 4; ++ct) {
    acc0[ct] = f32x4{0.f, 0.f, 0.f, 0.f};
    acc1[ct] = f32x4{0.f, 0.f, 0.f, 0.f};
  }
  f32x4 accs0 = f32x4{0.f, 0.f, 0.f, 0.f};
  f32x4 accs1 = f32x4{0.f, 0.f, 0.f, 0.f};

  auto load_win = [&](int wd) {
    Win W;
    int nb = wd * 32;
    W.qf0 = ld_bf8(qf_b + (size_t)(wd * 2) * 512 + l * 8);
    W.qf1 = ld_bf8(qf_b + (size_t)(wd * 2 + 1) * 512 + l * 8);
    W.qs0 = *(const f32x4*)(qsb + nb + lg * 4);
    W.qs1 = *(const f32x4*)(qsb + nb + 16 + lg * 4);
    W.rm0 = *(const f32x4*)(rmb + nb + lg * 4);
    W.rm1 = *(const f32x4*)(rmb + nb + 16 + lg * 4);
    const u16* vp = vq_b + (size_t)wd * 8192;
    W.vq0 = *(const uint4*)(vp);
    W.vq1 = *(const uint4*)(vp + 512);
    W.vq2 = *(const uint4*)(vp + 1024);
    W.vq3 = *(const uint4*)(vp + 1536);
    return W;
  };

  int wbase = nh * 64;                     // this wave's n-half
  Win cur = load_win(wbase);
  for (int i = 0; i < 64; ++i) {
    Win nxt = load_win(wbase + (i < 63 ? i + 1 : 63));  // depth-1 prefetch

    f32x4 e00 = mfma16(cur.qf0, kf0, f32x4{0.f, 0.f, 0.f, 0.f});
    f32x4 e01 = mfma16(cur.qf1, kf0, f32x4{0.f, 0.f, 0.f, 0.f});
    f32x4 e10 = mfma16(cur.qf0, kf1, f32x4{0.f, 0.f, 0.f, 0.f});
    f32x4 e11 = mfma16(cur.qf1, kf1, f32x4{0.f, 0.f, 0.f, 0.f});

    float p00[4], p01[4], p10[4], p11[4];
    #pragma unroll
    for (int r = 0; r < 4; ++r) {
      p00[r] = __builtin_amdgcn_exp2f(fmaf(cur.qs0[r], -ks0, fmaf(e00[r], L2E, -cur.rm0[r])));
      p01[r] = __builtin_amdgcn_exp2f(fmaf(cur.qs1[r], -ks0, fmaf(e01[r], L2E, -cur.rm1[r])));
      p10[r] = __builtin_amdgcn_exp2f(fmaf(cur.qs0[r], -ks1, fmaf(e10[r], L2E, -cur.rm0[r])));
      p11[r] = __builtin_amdgcn_exp2f(fmaf(cur.qs1[r], -ks1, fmaf(e11[r], L2E, -cur.rm1[r])));
    }

    U16x8 pb0, pb1;   // B-frag k-slots (permuted layout matches vq storage)
    #pragma unroll
    for (int r = 0; r < 4; ++r) {
      pb0.h[r] = (__bf16)p00[r]; pb0.h[4 + r] = (__bf16)p01[r];
      pb1.h[r] = (__bf16)p10[r]; pb1.h[4 + r] = (__bf16)p11[r];
    }

    // colsum on the matrix pipe
    accs0 = mfma16(ones, pb0.v, accs0);
    accs1 = mfma16(ones, pb1.v, accs1);

    U16x8 v0, v1, v2, v3;
    v0.q = cur.vq0; v1.q = cur.vq1; v2.q = cur.vq2; v3.q = cur.vq3;
    acc0[0] = mfma16(v0.v, pb0.v, acc0[0]);
    acc1[0] = mfma16(v0.v, pb1.v, acc1[0]);
    acc0[1] = mfma16(v1.v, pb0.v, acc0[1]);
    acc1[1] = mfma16(v1.v, pb1.v, acc1[1]);
    acc0[2] = mfma16(v2.v, pb0.v, acc0[2]);
    acc1[2] = mfma16(v2.v, pb1.v, acc1[2]);
    acc0[3] = mfma16(v3.v, pb0.v, acc0[3]);
    acc1[3] = mfma16(v3.v, pb1.v, acc1[3]);

    cur = nxt;
  }

  // publish colsum + nh=1 acc; one barrier; nh=0 adds + epilogue
  if (lg == 0) { csl[w][lr] = accs0[0]; csl[w][16 + lr] = accs1[0]; }
  if (nh == 1) {
    #pragma unroll
    for (int ct = 0; ct < 4; ++ct) {
      *(f32x4*)&accl[cq][(ct * 2 + 0) * 256 + l * 4] = acc0[ct];
      *(f32x4*)&accl[cq][(ct * 2 + 1) * 256 + l * 4] = acc1[ct];
    }
  }
  __syncthreads();
  if (nh == 0) {
    #pragma unroll
    for (int ct = 0; ct < 4; ++ct) {
      acc0[ct] += *(const f32x4*)&accl[cq][(ct * 2 + 0) * 256 + l * 4];
      acc1[ct] += *(const f32x4*)&accl[cq][(ct * 2 + 1) * 256 + l * 4];
    }
    float inv0 = __builtin_amdgcn_rcpf(1e-9f + csl[cq][lr] + csl[cq + 4][lr]);
    float inv1 = __builtin_amdgcn_rcpf(1e-9f + csl[cq][16 + lr] + csl[cq + 4][16 + lr]);

    #pragma unroll
    for (int ct = 0; ct < 4; ++ct) {
      {
        size_t base = ((size_t)(bN + m0 + lr)) * C_ + c0 + ct * 16 + lg * 4;
        uint2 xv2 = *(const uint2*)(xt + base);
        BF2 xa, xb; xa.w = xv2.x; xb.w = xv2.y;
        BF2 o0, o1;
        o0.h[0] = (__bf16)((float)xa.h[0] - acc0[ct][0] * inv0);
        o0.h[1] = (__bf16)((float)xa.h[1] - acc0[ct][1] * inv0);
        o1.h[0] = (__bf16)((float)xb.h[0] - acc0[ct][2] * inv0);
        o1.h[1] = (__bf16)((float)xb.h[1] - acc0[ct][3] * inv0);
        uint2 ov; ov.x = o0.w; ov.y = o1.w;
        *(uint2*)(diffb + base) = ov;
      }
      {
        size_t base = ((size_t)(bN + m0 + 16 + lr)) * C_ + c0 + ct * 16 + lg * 4;
        uint2 xv2 = *(const uint2*)(xt + base);
        BF2 xa, xb; xa.w = xv2.x; xb.w = xv2.y;
        BF2 o0, o1;
        o0.h[0] = (__bf16)((float)xa.h[0] - acc1[ct][0] * inv1);
        o0.h[1] = (__bf16)((float)xa.h[1] - acc1[ct][1] * inv1);
        o1.h[0] = (__bf16)((float)xb.h[0] - acc1[ct][2] * inv1);
        o1.h[1] = (__bf16)((float)xb.h[1] - acc1[ct][3] * inv1);
        uint2 ov; ov.x = o0.w; ov.y = o1.w;
        *(uint2*)(diffb + base) = ov;
      }
    }
  }
}

// ---------------- launch ----------------
extern "C" void kernel_launch(void* const* d_in, const int* in_sizes, int n_in,
                              void* d_out, int out_size, void* d_ws, size_t ws_size,
                              hipStream_t stream) {
  const float* x       = (const float*)d_in[0];
  const float* qk_w    = (const float*)d_in[1];
  const float* v_w     = (const float*)d_in[2];
  const float* v_b     = (const float*)d_in[3];
  const float* trans_w = (const float*)d_in[4];
  const float* trans_b = (const float*)d_in[5];
  const float* bn1s = (const float*)d_in[6];
  const float* bn1b = (const float*)d_in[7];
  const float* bn2s = (const float*)d_in[8];
  const float* bn2b = (const float*)d_in[9];
  const float* bn3s = (const float*)d_in[10];
  const float* bn3b = (const float*)d_in[11];
  const float* ans  = (const float*)d_in[12];
  const float* anb  = (const float*)d_in[13];
  float* out = (float*)d_out;
  char* ws = (char*)d_ws;

  if (ws_size < 27820032) return;

  u16*   xt    = (u16*)(ws + 0);          // [B][N][C] bf16   8 MB
  u16*   vq    = (u16*)(ws + 8388608);    // V fragment-major 8 MB
  u16*   diffb = (u16*)(ws + 16777216);   // [B][N][C] bf16   8 MB
  u16*   qfm   = (u16*)(ws + 25165824);   // q frags 1 MB
  u16*   kfm   = (u16*)(ws + 26214400);   // k frags 1 MB
  u16*   wv    = (u16*)(ws + 27262976);
  u16*   wt    = (u16*)(ws + 27394048);
  float* wqkt  = (float*)(ws + 27525120);
  float* qsg   = (float*)(ws + 27557888);
  float* ksg   = (float*)(ws + 27623424);
  float* rmg   = (float*)(ws + 27688960);

  k_prep<<<64, 256, 0, stream>>>(v_w, trans_w, qk_w, wv, wt, wqkt);
  k_xt<<<1024, 256, 0, stream>>>(x, xt);
  k_qk<<<256, 256, 0, stream>>>(x, wqkt, bn1s, bn1b, bn2s, bn2b, qfm, kfm, qsg, ksg);
  k_gemm256<0><<<512, 256, 0, stream>>>(wv, xt, v_b, bn3s, bn3b, nullptr, vq, nullptr);
  k_phaseA<<<512, 512, 0, stream>>>(qfm, kfm, qsg, ksg, rmg);
  k_phaseB<<<512, 512, 0, stream>>>(qfm, kfm, qsg, ksg, rmg, vq, xt, diffb);
  k_gemm256<1><<<512, 256, 0, stream>>>(wt, diffb, trans_b, ans, anb, x, nullptr, out);
}